// Round 1
// baseline (1551.889 us; speedup 1.0000x reference)
//
#include <hip/hip_runtime.h>
#include <hip/hip_bf16.h>
#include <math.h>

typedef __attribute__((ext_vector_type(8))) short bf16x8;
typedef __attribute__((ext_vector_type(4))) float f32x4;
typedef __hip_bfloat16 bf16;

__device__ __forceinline__ void gload_lds16(const void* g, void* l) {
  __builtin_amdgcn_global_load_lds((const __attribute__((address_space(1))) void*)g,
                                   (__attribute__((address_space(3))) void*)l,
                                   16, 0, 0);
}

__device__ __forceinline__ float gelu_erf(float x) {
  return 0.5f * x * (1.0f + erff(x * 0.70710678118654752f));
}

// ---------------- convert f32 -> bf16 (vectorized) ----------------
__global__ __launch_bounds__(256) void k_cvt_bf16(const float* __restrict__ in,
                                                  bf16* __restrict__ out, int n4) {
  int i = blockIdx.x * 256 + threadIdx.x;
  const int stride = gridDim.x * 256;
  for (; i < n4; i += stride) {
    float4 v = reinterpret_cast<const float4*>(in)[i];
    bf16* o = out + (size_t)i * 4;
    o[0] = __float2bfloat16(v.x);
    o[1] = __float2bfloat16(v.y);
    o[2] = __float2bfloat16(v.z);
    o[3] = __float2bfloat16(v.w);
  }
}

// ---------------- transpose f32 [R][C] -> bf16 [C][R] ----------------
__global__ __launch_bounds__(256) void k_transpose_w(const float* __restrict__ in,
                                                     bf16* __restrict__ out,
                                                     int R, int C) {
  __shared__ float tile[32][33];
  const int c0 = blockIdx.x * 32, r0 = blockIdx.y * 32;
  const int tx = threadIdx.x & 31, ty = threadIdx.x >> 5;
  for (int i = 0; i < 32; i += 8)
    tile[ty + i][tx] = in[(size_t)(r0 + ty + i) * C + c0 + tx];
  __syncthreads();
  for (int i = 0; i < 32; i += 8)
    out[(size_t)(c0 + ty + i) * R + r0 + tx] = __float2bfloat16(tile[tx][ty + i]);
}

// ------------- per-head V transpose: [B*S][E] -> [(b*H+h)*128 + d][S] -------------
__global__ __launch_bounds__(256) void k_transpose_v(const bf16* __restrict__ Vb,
                                                     bf16* __restrict__ Vt) {
  __shared__ bf16 tile[32][34];
  const int bh = blockIdx.z;
  const int b = bh >> 3, h = bh & 7;
  const int s0 = blockIdx.x * 32, d0 = blockIdx.y * 32;
  const int tx = threadIdx.x & 31, ty = threadIdx.x >> 5;
  for (int i = 0; i < 32; i += 8)
    tile[ty + i][tx] = Vb[((size_t)b * 512 + s0 + ty + i) * 1024 + h * 128 + d0 + tx];
  __syncthreads();
  for (int i = 0; i < 32; i += 8)
    Vt[((size_t)bh * 128 + d0 + ty + i) * 512 + s0 + tx] = tile[tx][ty + i];
}

// ---------------- 128x128 tile bf16 GEMM, B^T input (m97 structure) ----------------
// C[M][N] = A[M][K] * Bt[N][K]^T + bias;  EPI: 0=bf16 out, 1=gelu->bf16, 2=f32 out(+=)
template <int EPI, bool ACC>
__global__ __launch_bounds__(256) void k_gemm_bt(
    const bf16* __restrict__ A, const bf16* __restrict__ Bt,
    const float* __restrict__ bias, void* __restrict__ Cout,
    int K, int lda, int ldb, int ldc) {
  __shared__ bf16 As[128 * 32];
  __shared__ bf16 Bs[128 * 32];
  const int t = threadIdx.x, w = t >> 6, l = t & 63;
  const int bm = blockIdx.y, bn = blockIdx.x;
  const int wr = w & 1, wc = w >> 1;
  const int lq = l >> 4, lr = l & 15;

  // staging: 512 16B-chunks per tile, 256 threads x 2 iters; LDS dest is linear.
  const int c0 = w * 64 + l, c1 = c0 + 256;
  const int r0 = c0 >> 2, k0o = (c0 & 3) * 8;
  const int r1 = c1 >> 2, k1o = (c1 & 3) * 8;
  const bf16* Ab = A + (size_t)(bm * 128) * lda;
  const bf16* Bb = Bt + (size_t)(bn * 128) * ldb;
  bf16* As0 = &As[w * 512];
  bf16* As1 = &As[2048 + w * 512];
  bf16* Bs0 = &Bs[w * 512];
  bf16* Bs1 = &Bs[2048 + w * 512];

  f32x4 acc[4][4];
#pragma unroll
  for (int m = 0; m < 4; ++m)
#pragma unroll
    for (int n = 0; n < 4; ++n) acc[m][n] = (f32x4){0.f, 0.f, 0.f, 0.f};

  for (int kt = 0; kt < K; kt += 32) {
    gload_lds16(Ab + (size_t)r0 * lda + kt + k0o, As0);
    gload_lds16(Ab + (size_t)r1 * lda + kt + k1o, As1);
    gload_lds16(Bb + (size_t)r0 * ldb + kt + k0o, Bs0);
    gload_lds16(Bb + (size_t)r1 * ldb + kt + k1o, Bs1);
    asm volatile("s_waitcnt vmcnt(0)" ::: "memory");
    __syncthreads();
    bf16x8 af[4], bfrg[4];
#pragma unroll
    for (int m = 0; m < 4; ++m)
      af[m] = *(const bf16x8*)&As[(wr * 64 + m * 16 + lr) * 32 + lq * 8];
#pragma unroll
    for (int n = 0; n < 4; ++n)
      bfrg[n] = *(const bf16x8*)&Bs[(wc * 64 + n * 16 + lr) * 32 + lq * 8];
#pragma unroll
    for (int m = 0; m < 4; ++m)
#pragma unroll
      for (int n = 0; n < 4; ++n)
        acc[m][n] = __builtin_amdgcn_mfma_f32_16x16x32_bf16(af[m], bfrg[n], acc[m][n], 0, 0, 0);
    __syncthreads();
  }

  const int rowb = bm * 128 + wr * 64;
  const int colb = bn * 128 + wc * 64;
#pragma unroll
  for (int m = 0; m < 4; ++m) {
#pragma unroll
    for (int n = 0; n < 4; ++n) {
      const int col = colb + n * 16 + lr;
      const float bv = bias ? bias[col] : 0.0f;
#pragma unroll
      for (int i = 0; i < 4; ++i) {
        const int row = rowb + m * 16 + lq * 4 + i;
        float v = acc[m][n][i] + bv;
        if (EPI == 1) v = gelu_erf(v);
        if (EPI <= 1) {
          ((bf16*)Cout)[(size_t)row * ldc + col] = __float2bfloat16(v);
        } else {
          float* Cf = (float*)Cout;
          const size_t idx = (size_t)row * ldc + col;
          if (ACC) v += Cf[idx];
          Cf[idx] = v;
        }
      }
    }
  }
}

// ---------------- attention: one (b,h,32-row q-tile) per block ----------------
__global__ __launch_bounds__(256) void k_attn(const bf16* __restrict__ Qg,
                                              const bf16* __restrict__ Kg,
                                              const bf16* __restrict__ Vt,
                                              bf16* __restrict__ Og) {
  __shared__ float sc[32][516];   // fp32 scores, stride keeps 16B align, 2-way max conflict
  __shared__ bf16 Pl[32][520];
  __shared__ bf16 Ql[32][128];
  __shared__ float rsum[32];
  const int bh = blockIdx.y, b = bh >> 3, h = bh & 7;
  const int q0 = blockIdx.x * 32;
  const int t = threadIdx.x, w = t >> 6, l = t & 63;
  const int lq = l >> 4, lr = l & 15;

  // load Q tile (32x128 bf16)
  const bf16* qbase = Qg + ((size_t)b * 512 + q0) * 1024 + h * 128;
  for (int c = t; c < 512; c += 256) {
    const int r = c >> 4, cc = (c & 15) * 8;
    *(bf16x8*)&Ql[r][cc] = *(const bf16x8*)(qbase + (size_t)r * 1024 + cc);
  }
  __syncthreads();

  // scores = Q K^T : wave w does row-tile rt (16 rows), col half ch (256 cols)
  const int rt = w & 1, ch = w >> 1;
  bf16x8 afr[4];
#pragma unroll
  for (int d0 = 0; d0 < 4; ++d0)
    afr[d0] = *(const bf16x8*)&Ql[rt * 16 + lr][d0 * 32 + lq * 8];
  const bf16* kbase = Kg + (size_t)b * 512 * 1024 + h * 128;
  for (int ct = 0; ct < 16; ++ct) {
    const int col0 = ch * 256 + ct * 16;
    f32x4 acc = (f32x4){0.f, 0.f, 0.f, 0.f};
#pragma unroll
    for (int d0 = 0; d0 < 4; ++d0) {
      bf16x8 bfrg = *(const bf16x8*)(kbase + (size_t)(col0 + lr) * 1024 + d0 * 32 + lq * 8);
      acc = __builtin_amdgcn_mfma_f32_16x16x32_bf16(afr[d0], bfrg, acc, 0, 0, 0);
    }
#pragma unroll
    for (int i = 0; i < 4; ++i)
      sc[rt * 16 + lq * 4 + i][col0 + lr] = acc[i];
  }
  __syncthreads();

  // wave-parallel softmax: 8 rows/wave, 8 lanes/row
  {
    const int r = w * 8 + (l >> 3), sub = l & 7;
    float m = -1e30f;
    for (int c = sub * 4; c < 512; c += 32) {
      float4 v = *(const float4*)&sc[r][c];
      m = fmaxf(m, fmaxf(fmaxf(v.x, v.y), fmaxf(v.z, v.w)));
    }
    m = fmaxf(m, __shfl_xor(m, 1));
    m = fmaxf(m, __shfl_xor(m, 2));
    m = fmaxf(m, __shfl_xor(m, 4));
    float s = 0.f;
    for (int c = sub * 4; c < 512; c += 32) {
      float4 v = *(const float4*)&sc[r][c];
      const float e0 = __expf(v.x - m), e1 = __expf(v.y - m),
                  e2 = __expf(v.z - m), e3 = __expf(v.w - m);
      s += (e0 + e1) + (e2 + e3);
      Pl[r][c + 0] = __float2bfloat16(e0);
      Pl[r][c + 1] = __float2bfloat16(e1);
      Pl[r][c + 2] = __float2bfloat16(e2);
      Pl[r][c + 3] = __float2bfloat16(e3);
    }
    s += __shfl_xor(s, 1);
    s += __shfl_xor(s, 2);
    s += __shfl_xor(s, 4);
    if (sub == 0) rsum[r] = s;
  }
  __syncthreads();

  // o = P V : wave w does row-tile rt, d-cols [(w>>1)*64, +64)
  const bf16* vbase = Vt + (size_t)bh * 128 * 512;
  f32x4 oacc[4];
#pragma unroll
  for (int n = 0; n < 4; ++n) oacc[n] = (f32x4){0.f, 0.f, 0.f, 0.f};
  for (int s0 = 0; s0 < 512; s0 += 32) {
    bf16x8 pa = *(const bf16x8*)&Pl[rt * 16 + lr][s0 + lq * 8];
#pragma unroll
    for (int n = 0; n < 4; ++n) {
      const int dcol = ((w >> 1) * 4 + n) * 16;
      bf16x8 vb = *(const bf16x8*)(vbase + (size_t)(dcol + lr) * 512 + s0 + lq * 8);
      oacc[n] = __builtin_amdgcn_mfma_f32_16x16x32_bf16(pa, vb, oacc[n], 0, 0, 0);
    }
  }
#pragma unroll
  for (int n = 0; n < 4; ++n) {
    const int dcol = ((w >> 1) * 4 + n) * 16;
#pragma unroll
    for (int i = 0; i < 4; ++i) {
      const int row = rt * 16 + lq * 4 + i;
      const float val = oacc[n][i] / rsum[row];
      Og[((size_t)b * 512 + q0 + row) * 1024 + h * 128 + dcol + lr] = __float2bfloat16(val);
    }
  }
}

extern "C" void kernel_launch(void* const* d_in, const int* in_sizes, int n_in,
                              void* d_out, int out_size, void* d_ws, size_t ws_size,
                              hipStream_t stream) {
  (void)in_sizes; (void)n_in; (void)out_size; (void)ws_size;
  const float* x  = (const float*)d_in[0];
  const float* Wq = (const float*)d_in[1];
  const float* bq = (const float*)d_in[2];
  const float* Wk = (const float*)d_in[3];
  const float* bk = (const float*)d_in[4];
  const float* Wv = (const float*)d_in[5];
  const float* bv = (const float*)d_in[6];
  const float* W1 = (const float*)d_in[7];
  const float* b1 = (const float*)d_in[8];
  const float* W2 = (const float*)d_in[9];
  const float* b2 = (const float*)d_in[10];
  float* out = (float*)d_out;
  char* ws = (char*)d_ws;
  constexpr size_t MB = 1ull << 20;

  // workspace layout (peak 198 MB, with overlays of dead buffers)
  bf16* XB  = (bf16*)(ws + 0);        // x bf16            [16384][1024]  32MB
  bf16* WQT = (bf16*)(ws + 32 * MB);  // Wq^T              [1024][1024]    2MB
  bf16* WKT = (bf16*)(ws + 34 * MB);
  bf16* WVT = (bf16*)(ws + 36 * MB);
  bf16* W1T = (bf16*)(ws + 38 * MB);  // W1^T              [8192][1024]   16MB
  bf16* W2T = (bf16*)(ws + 54 * MB);  // W2^T              [1024][8192]   16MB
  bf16* OB  = (bf16*)(ws + 70 * MB);  // attn out          [16384][1024]  32MB
  bf16* QB  = (bf16*)(ws + 102 * MB); // Q                 [16384][1024]  32MB
  bf16* KB  = (bf16*)(ws + 134 * MB); // K                 [16384][1024]  32MB
  bf16* VB  = (bf16*)(ws + 166 * MB); // V (pre-transpose)                32MB
  bf16* VT  = (bf16*)(ws + 0);        // V^T per head [bh*128+d][512] — overlays dead XB
  bf16* HC  = (bf16*)(ws + 102 * MB); // hid chunk [16384][2048] — overlays dead QB/KB

  // 1. precision conversion + weight transposes (to B^T layout)
  k_cvt_bf16<<<2048, 256, 0, stream>>>(x, XB, (16384 * 1024) / 4);
  k_transpose_w<<<dim3(32, 32), 256, 0, stream>>>(Wq, WQT, 1024, 1024);
  k_transpose_w<<<dim3(32, 32), 256, 0, stream>>>(Wk, WKT, 1024, 1024);
  k_transpose_w<<<dim3(32, 32), 256, 0, stream>>>(Wv, WVT, 1024, 1024);
  k_transpose_w<<<dim3(256, 32), 256, 0, stream>>>(W1, W1T, 1024, 8192);
  k_transpose_w<<<dim3(32, 256), 256, 0, stream>>>(W2, W2T, 8192, 1024);

  // 2. QKV projections (M=16384, N=1024, K=1024)
  k_gemm_bt<0, false><<<dim3(8, 128), 256, 0, stream>>>(XB, WQT, bq, QB, 1024, 1024, 1024, 1024);
  k_gemm_bt<0, false><<<dim3(8, 128), 256, 0, stream>>>(XB, WKT, bk, KB, 1024, 1024, 1024, 1024);
  k_gemm_bt<0, false><<<dim3(8, 128), 256, 0, stream>>>(XB, WVT, bv, VB, 1024, 1024, 1024, 1024);

  // 3. per-head V transpose, then attention
  k_transpose_v<<<dim3(16, 4, 256), 256, 0, stream>>>(VB, VT);
  k_attn<<<dim3(16, 256), 256, 0, stream>>>(QB, KB, VT, OB);

  // 4. FFN chunked over F (4 x 2048) to bound workspace; FFN2 accumulates fp32
  for (int chk = 0; chk < 4; ++chk) {
    k_gemm_bt<1, false><<<dim3(16, 128), 256, 0, stream>>>(
        OB, W1T + (size_t)chk * 2048 * 1024, b1 + chk * 2048, HC, 1024, 1024, 1024, 2048);
    if (chk == 0)
      k_gemm_bt<2, false><<<dim3(8, 128), 256, 0, stream>>>(
          HC, W2T + chk * 2048, b2, out, 2048, 2048, 8192, 1024);
    else
      k_gemm_bt<2, true><<<dim3(8, 128), 256, 0, stream>>>(
          HC, W2T + chk * 2048, nullptr, out, 2048, 2048, 8192, 1024);
  }
}

// Round 2
// 1412.429 us; speedup vs baseline: 1.0987x; 1.0987x over previous
//
#include <hip/hip_runtime.h>
#include <hip/hip_bf16.h>
#include <math.h>

typedef __attribute__((ext_vector_type(8))) short bf16x8;
typedef __attribute__((ext_vector_type(4))) float f32x4;
typedef __hip_bfloat16 bf16;

__device__ __forceinline__ void gload_lds16(const void* g, void* l) {
  __builtin_amdgcn_global_load_lds((const __attribute__((address_space(1))) void*)g,
                                   (__attribute__((address_space(3))) void*)l,
                                   16, 0, 0);
}

__device__ __forceinline__ float gelu_erf(float x) {
  return 0.5f * x * (1.0f + erff(x * 0.70710678118654752f));
}

// ---------------- convert f32 -> bf16 (vectorized) ----------------
__global__ __launch_bounds__(256) void k_cvt_bf16(const float* __restrict__ in,
                                                  bf16* __restrict__ out, int n4) {
  int i = blockIdx.x * 256 + threadIdx.x;
  const int stride = gridDim.x * 256;
  for (; i < n4; i += stride) {
    float4 v = reinterpret_cast<const float4*>(in)[i];
    bf16* o = out + (size_t)i * 4;
    o[0] = __float2bfloat16(v.x);
    o[1] = __float2bfloat16(v.y);
    o[2] = __float2bfloat16(v.z);
    o[3] = __float2bfloat16(v.w);
  }
}

// ---------------- transpose f32 [R][C] -> bf16 [C][R] ----------------
__global__ __launch_bounds__(256) void k_transpose_w(const float* __restrict__ in,
                                                     bf16* __restrict__ out,
                                                     int R, int C) {
  __shared__ float tile[32][33];
  const int c0 = blockIdx.x * 32, r0 = blockIdx.y * 32;
  const int tx = threadIdx.x & 31, ty = threadIdx.x >> 5;
  for (int i = 0; i < 32; i += 8)
    tile[ty + i][tx] = in[(size_t)(r0 + ty + i) * C + c0 + tx];
  __syncthreads();
  for (int i = 0; i < 32; i += 8)
    out[(size_t)(c0 + ty + i) * R + r0 + tx] = __float2bfloat16(tile[tx][ty + i]);
}

// ------------- per-head V transpose: [B*S][E] -> [(b*H+h)*128 + d][S] -------------
__global__ __launch_bounds__(256) void k_transpose_v(const bf16* __restrict__ Vb,
                                                     bf16* __restrict__ Vt) {
  __shared__ bf16 tile[32][34];
  const int bh = blockIdx.z;
  const int b = bh >> 3, h = bh & 7;
  const int s0 = blockIdx.x * 32, d0 = blockIdx.y * 32;
  const int tx = threadIdx.x & 31, ty = threadIdx.x >> 5;
  for (int i = 0; i < 32; i += 8)
    tile[ty + i][tx] = Vb[((size_t)b * 512 + s0 + ty + i) * 1024 + h * 128 + d0 + tx];
  __syncthreads();
  for (int i = 0; i < 32; i += 8)
    Vt[((size_t)bh * 128 + d0 + ty + i) * 512 + s0 + tx] = tile[tx][ty + i];
}

// ---------------- 128x128 tile bf16 GEMM, B^T input (m97 structure) ----------------
// C[M][N] = A[M][K] * Bt[N][K]^T + bias;  EPI: 0=bf16 out, 1=gelu->bf16, 2=f32 out(+=)
// XCD-aware bijective block swizzle (T1): all launches have nwg % 8 == 0.
template <int EPI, bool ACC>
__global__ __launch_bounds__(256) void k_gemm_bt(
    const bf16* __restrict__ A, const bf16* __restrict__ Bt,
    const float* __restrict__ bias, void* __restrict__ Cout,
    int K, int lda, int ldb, int ldc) {
  __shared__ bf16 As[128 * 32];
  __shared__ bf16 Bs[128 * 32];
  const int t = threadIdx.x, w = t >> 6, l = t & 63;
  const int gx = gridDim.x;
  const int nwg = gx * gridDim.y;
  int bid = blockIdx.y * gx + blockIdx.x;
  bid = (bid & 7) * (nwg >> 3) + (bid >> 3);  // XCD swizzle (nwg%8==0)
  const int bm = bid / gx, bn = bid % gx;
  const int wr = w & 1, wc = w >> 1;
  const int lq = l >> 4, lr = l & 15;

  // staging: 512 16B-chunks per tile, 256 threads x 2 iters; LDS dest is linear.
  const int c0 = w * 64 + l, c1 = c0 + 256;
  const int r0 = c0 >> 2, k0o = (c0 & 3) * 8;
  const int r1 = c1 >> 2, k1o = (c1 & 3) * 8;
  const bf16* Ab = A + (size_t)(bm * 128) * lda;
  const bf16* Bb = Bt + (size_t)(bn * 128) * ldb;
  bf16* As0 = &As[w * 512];
  bf16* As1 = &As[2048 + w * 512];
  bf16* Bs0 = &Bs[w * 512];
  bf16* Bs1 = &Bs[2048 + w * 512];

  f32x4 acc[4][4];
#pragma unroll
  for (int m = 0; m < 4; ++m)
#pragma unroll
    for (int n = 0; n < 4; ++n) acc[m][n] = (f32x4){0.f, 0.f, 0.f, 0.f};

  for (int kt = 0; kt < K; kt += 32) {
    gload_lds16(Ab + (size_t)r0 * lda + kt + k0o, As0);
    gload_lds16(Ab + (size_t)r1 * lda + kt + k1o, As1);
    gload_lds16(Bb + (size_t)r0 * ldb + kt + k0o, Bs0);
    gload_lds16(Bb + (size_t)r1 * ldb + kt + k1o, Bs1);
    asm volatile("s_waitcnt vmcnt(0)" ::: "memory");
    __syncthreads();
    bf16x8 af[4], bfrg[4];
#pragma unroll
    for (int m = 0; m < 4; ++m)
      af[m] = *(const bf16x8*)&As[(wr * 64 + m * 16 + lr) * 32 + lq * 8];
#pragma unroll
    for (int n = 0; n < 4; ++n)
      bfrg[n] = *(const bf16x8*)&Bs[(wc * 64 + n * 16 + lr) * 32 + lq * 8];
#pragma unroll
    for (int m = 0; m < 4; ++m)
#pragma unroll
      for (int n = 0; n < 4; ++n)
        acc[m][n] = __builtin_amdgcn_mfma_f32_16x16x32_bf16(af[m], bfrg[n], acc[m][n], 0, 0, 0);
    __syncthreads();
  }

  const int rowb = bm * 128 + wr * 64;
  const int colb = bn * 128 + wc * 64;
#pragma unroll
  for (int m = 0; m < 4; ++m) {
#pragma unroll
    for (int n = 0; n < 4; ++n) {
      const int col = colb + n * 16 + lr;
      const float bv = bias ? bias[col] : 0.0f;
#pragma unroll
      for (int i = 0; i < 4; ++i) {
        const int row = rowb + m * 16 + lq * 4 + i;
        float v = acc[m][n][i] + bv;
        if (EPI == 1) v = gelu_erf(v);
        if (EPI <= 1) {
          ((bf16*)Cout)[(size_t)row * ldc + col] = __float2bfloat16(v);
        } else {
          float* Cf = (float*)Cout;
          const size_t idx = (size_t)row * ldc + col;
          if (ACC) v += Cf[idx];
          Cf[idx] = v;
        }
      }
    }
  }
}

// ---------------- attention v2: register-resident softmax ----------------
// one (b,h,32-row q-tile) per block; scores stay in MFMA accumulators.
// LDS: P (bf16, 33.3KB) + reduce bufs (0.5KB) -> ~34KB => 3 blocks/CU @132 VGPR.
__global__ __launch_bounds__(256) void k_attn(const bf16* __restrict__ Qg,
                                              const bf16* __restrict__ Kg,
                                              const bf16* __restrict__ Vt,
                                              bf16* __restrict__ Og) {
  __shared__ bf16 Pl[32][520];
  __shared__ float redm[2][32];
  __shared__ float reds[2][32];
  // XCD swizzle over flattened grid (nwg = 16*256 = 4096, %8==0)
  int bid = blockIdx.y * 16 + blockIdx.x;
  bid = (bid & 7) * (4096 >> 3) + (bid >> 3);
  const int bh = bid / 16, q0 = (bid % 16) * 32;
  const int b = bh >> 3, h = bh & 7;
  const int t = threadIdx.x, w = t >> 6, l = t & 63;
  const int lq = l >> 4, lr = l & 15;
  const int rt = w & 1, ch = w >> 1;
  const int myrow = rt * 16 + lq * 4;  // +i gives the 4 C-layout rows this lane holds

  // Q fragments directly from global (L2-hot): rows rt*16+lr, k = d0*32 + lq*8
  const bf16* qbase = Qg + ((size_t)b * 512 + q0 + rt * 16 + lr) * 1024 + h * 128;
  bf16x8 afr[4];
#pragma unroll
  for (int d0 = 0; d0 < 4; ++d0)
    afr[d0] = *(const bf16x8*)(qbase + d0 * 32 + lq * 8);

  // QK^T into registers: wave covers rows rt*16..+16, cols ch*256..+256
  const bf16* kbase = Kg + (size_t)b * 512 * 1024 + h * 128;
  f32x4 sc[16];
#pragma unroll
  for (int ct = 0; ct < 16; ++ct) {
    const int col0 = ch * 256 + ct * 16;
    f32x4 acc = (f32x4){0.f, 0.f, 0.f, 0.f};
#pragma unroll
    for (int d0 = 0; d0 < 4; ++d0) {
      bf16x8 bfrg = *(const bf16x8*)(kbase + (size_t)(col0 + lr) * 1024 + d0 * 32 + lq * 8);
      acc = __builtin_amdgcn_mfma_f32_16x16x32_bf16(afr[d0], bfrg, acc, 0, 0, 0);
    }
    sc[ct] = acc;
  }

  // row-max over this wave's 256 cols: per-lane partial, then xor-reduce across lr
  float m4[4];
#pragma unroll
  for (int i = 0; i < 4; ++i) {
    float m = sc[0][i];
#pragma unroll
    for (int ct = 1; ct < 16; ++ct) m = fmaxf(m, sc[ct][i]);
    m4[i] = m;
  }
#pragma unroll
  for (int i = 0; i < 4; ++i) {
    m4[i] = fmaxf(m4[i], __shfl_xor(m4[i], 1));
    m4[i] = fmaxf(m4[i], __shfl_xor(m4[i], 2));
    m4[i] = fmaxf(m4[i], __shfl_xor(m4[i], 4));
    m4[i] = fmaxf(m4[i], __shfl_xor(m4[i], 8));
  }
  if (lr == 0) {
#pragma unroll
    for (int i = 0; i < 4; ++i) redm[ch][myrow + i] = m4[i];
  }
  __syncthreads();
  float fm[4];
#pragma unroll
  for (int i = 0; i < 4; ++i)
    fm[i] = fmaxf(redm[0][myrow + i], redm[1][myrow + i]);

  // exp, partial row-sum, and P -> LDS (bf16)
  float s4[4] = {0.f, 0.f, 0.f, 0.f};
#pragma unroll
  for (int ct = 0; ct < 16; ++ct) {
    const int col = ch * 256 + ct * 16 + lr;
#pragma unroll
    for (int i = 0; i < 4; ++i) {
      const float e = __expf(sc[ct][i] - fm[i]);
      s4[i] += e;
      Pl[myrow + i][col] = __float2bfloat16(e);
    }
  }
#pragma unroll
  for (int i = 0; i < 4; ++i) {
    s4[i] += __shfl_xor(s4[i], 1);
    s4[i] += __shfl_xor(s4[i], 2);
    s4[i] += __shfl_xor(s4[i], 4);
    s4[i] += __shfl_xor(s4[i], 8);
  }
  if (lr == 0) {
#pragma unroll
    for (int i = 0; i < 4; ++i) reds[ch][myrow + i] = s4[i];
  }
  __syncthreads();

  // o = P V : wave w does row-tile rt, d-cols [(w>>1)*64, +64)
  const bf16* vbase = Vt + (size_t)bh * 128 * 512;
  f32x4 oacc[4];
#pragma unroll
  for (int n = 0; n < 4; ++n) oacc[n] = (f32x4){0.f, 0.f, 0.f, 0.f};
  for (int s0 = 0; s0 < 512; s0 += 32) {
    bf16x8 pa = *(const bf16x8*)&Pl[rt * 16 + lr][s0 + lq * 8];
#pragma unroll
    for (int n = 0; n < 4; ++n) {
      const int dcol = (ch * 4 + n) * 16;
      bf16x8 vb = *(const bf16x8*)(vbase + (size_t)(dcol + lr) * 512 + s0 + lq * 8);
      oacc[n] = __builtin_amdgcn_mfma_f32_16x16x32_bf16(pa, vb, oacc[n], 0, 0, 0);
    }
  }
#pragma unroll
  for (int n = 0; n < 4; ++n) {
    const int dcol = (ch * 4 + n) * 16;
#pragma unroll
    for (int i = 0; i < 4; ++i) {
      const int row = myrow + i;
      const float rs = reds[0][row] + reds[1][row];
      const float val = oacc[n][i] / rs;
      Og[((size_t)b * 512 + q0 + row) * 1024 + h * 128 + dcol + lr] = __float2bfloat16(val);
    }
  }
}

extern "C" void kernel_launch(void* const* d_in, const int* in_sizes, int n_in,
                              void* d_out, int out_size, void* d_ws, size_t ws_size,
                              hipStream_t stream) {
  (void)in_sizes; (void)n_in; (void)out_size; (void)ws_size;
  const float* x  = (const float*)d_in[0];
  const float* Wq = (const float*)d_in[1];
  const float* bq = (const float*)d_in[2];
  const float* Wk = (const float*)d_in[3];
  const float* bk = (const float*)d_in[4];
  const float* Wv = (const float*)d_in[5];
  const float* bv = (const float*)d_in[6];
  const float* W1 = (const float*)d_in[7];
  const float* b1 = (const float*)d_in[8];
  const float* W2 = (const float*)d_in[9];
  const float* b2 = (const float*)d_in[10];
  float* out = (float*)d_out;
  char* ws = (char*)d_ws;
  constexpr size_t MB = 1ull << 20;

  // workspace layout (peak 198 MB, with overlays of dead buffers)
  bf16* XB  = (bf16*)(ws + 0);        // x bf16            [16384][1024]  32MB
  bf16* WQT = (bf16*)(ws + 32 * MB);  // Wq^T              [1024][1024]    2MB
  bf16* WKT = (bf16*)(ws + 34 * MB);
  bf16* WVT = (bf16*)(ws + 36 * MB);
  bf16* W1T = (bf16*)(ws + 38 * MB);  // W1^T              [8192][1024]   16MB
  bf16* W2T = (bf16*)(ws + 54 * MB);  // W2^T              [1024][8192]   16MB
  bf16* OB  = (bf16*)(ws + 70 * MB);  // attn out          [16384][1024]  32MB
  bf16* QB  = (bf16*)(ws + 102 * MB); // Q                 [16384][1024]  32MB
  bf16* KB  = (bf16*)(ws + 134 * MB); // K                 [16384][1024]  32MB
  bf16* VB  = (bf16*)(ws + 166 * MB); // V (pre-transpose)                32MB
  bf16* VT  = (bf16*)(ws + 0);        // V^T per head [bh*128+d][512] — overlays dead XB
  bf16* HC  = (bf16*)(ws + 102 * MB); // hid chunk [16384][2048] — overlays dead QB/KB

  // 1. precision conversion + weight transposes (to B^T layout)
  k_cvt_bf16<<<2048, 256, 0, stream>>>(x, XB, (16384 * 1024) / 4);
  k_transpose_w<<<dim3(32, 32), 256, 0, stream>>>(Wq, WQT, 1024, 1024);
  k_transpose_w<<<dim3(32, 32), 256, 0, stream>>>(Wk, WKT, 1024, 1024);
  k_transpose_w<<<dim3(32, 32), 256, 0, stream>>>(Wv, WVT, 1024, 1024);
  k_transpose_w<<<dim3(256, 32), 256, 0, stream>>>(W1, W1T, 1024, 8192);
  k_transpose_w<<<dim3(32, 256), 256, 0, stream>>>(W2, W2T, 8192, 1024);

  // 2. QKV projections (M=16384, N=1024, K=1024)
  k_gemm_bt<0, false><<<dim3(8, 128), 256, 0, stream>>>(XB, WQT, bq, QB, 1024, 1024, 1024, 1024);
  k_gemm_bt<0, false><<<dim3(8, 128), 256, 0, stream>>>(XB, WKT, bk, KB, 1024, 1024, 1024, 1024);
  k_gemm_bt<0, false><<<dim3(8, 128), 256, 0, stream>>>(XB, WVT, bv, VB, 1024, 1024, 1024, 1024);

  // 3. per-head V transpose, then attention
  k_transpose_v<<<dim3(16, 4, 256), 256, 0, stream>>>(VB, VT);
  k_attn<<<dim3(16, 256), 256, 0, stream>>>(QB, KB, VT, OB);

  // 4. FFN chunked over F (4 x 2048) to bound workspace; FFN2 accumulates fp32
  for (int chk = 0; chk < 4; ++chk) {
    k_gemm_bt<1, false><<<dim3(16, 128), 256, 0, stream>>>(
        OB, W1T + (size_t)chk * 2048 * 1024, b1 + chk * 2048, HC, 1024, 1024, 1024, 2048);
    if (chk == 0)
      k_gemm_bt<2, false><<<dim3(8, 128), 256, 0, stream>>>(
          HC, W2T + chk * 2048, b2, out, 2048, 2048, 8192, 1024);
    else
      k_gemm_bt<2, true><<<dim3(8, 128), 256, 0, stream>>>(
          HC, W2T + chk * 2048, nullptr, out, 2048, 2048, 8192, 1024);
  }
}

// Round 4
// 1102.006 us; speedup vs baseline: 1.4082x; 1.2817x over previous
//
#include <hip/hip_runtime.h>
#include <hip/hip_bf16.h>
#include <math.h>

typedef __attribute__((ext_vector_type(8))) short bf16x8;
typedef __attribute__((ext_vector_type(4))) float f32x4;
typedef __hip_bfloat16 bf16;

__device__ __forceinline__ void gload_lds16(const void* g, void* l) {
  __builtin_amdgcn_global_load_lds((const __attribute__((address_space(1))) void*)g,
                                   (__attribute__((address_space(3))) void*)l,
                                   16, 0, 0);
}

__device__ __forceinline__ float gelu_erf(float x) {
  return 0.5f * x * (1.0f + erff(x * 0.70710678118654752f));
}

// ---------------- convert f32 -> bf16 (vectorized) ----------------
__global__ __launch_bounds__(256) void k_cvt_bf16(const float* __restrict__ in,
                                                  bf16* __restrict__ out, int n4) {
  int i = blockIdx.x * 256 + threadIdx.x;
  const int stride = gridDim.x * 256;
  for (; i < n4; i += stride) {
    float4 v = reinterpret_cast<const float4*>(in)[i];
    bf16* o = out + (size_t)i * 4;
    o[0] = __float2bfloat16(v.x);
    o[1] = __float2bfloat16(v.y);
    o[2] = __float2bfloat16(v.z);
    o[3] = __float2bfloat16(v.w);
  }
}

// ---------------- transpose f32 [R][C] -> bf16 [C][R] ----------------
__global__ __launch_bounds__(256) void k_transpose_w(const float* __restrict__ in,
                                                     bf16* __restrict__ out,
                                                     int R, int C) {
  __shared__ float tile[32][33];
  const int c0 = blockIdx.x * 32, r0 = blockIdx.y * 32;
  const int tx = threadIdx.x & 31, ty = threadIdx.x >> 5;
  for (int i = 0; i < 32; i += 8)
    tile[ty + i][tx] = in[(size_t)(r0 + ty + i) * C + c0 + tx];
  __syncthreads();
  for (int i = 0; i < 32; i += 8)
    out[(size_t)(c0 + ty + i) * R + r0 + tx] = __float2bfloat16(tile[tx][ty + i]);
}

// ------------- per-head V transpose: [B*S][E] -> [(b*H+h)*128 + d][S] -------------
__global__ __launch_bounds__(256) void k_transpose_v(const bf16* __restrict__ Vb,
                                                     bf16* __restrict__ Vt) {
  __shared__ bf16 tile[32][34];
  const int bh = blockIdx.z;
  const int b = bh >> 3, h = bh & 7;
  const int s0 = blockIdx.x * 32, d0 = blockIdx.y * 32;
  const int tx = threadIdx.x & 31, ty = threadIdx.x >> 5;
  for (int i = 0; i < 32; i += 8)
    tile[ty + i][tx] = Vb[((size_t)b * 512 + s0 + ty + i) * 1024 + h * 128 + d0 + tx];
  __syncthreads();
  for (int i = 0; i < 32; i += 8)
    Vt[((size_t)bh * 128 + d0 + ty + i) * 512 + s0 + tx] = tile[tx][ty + i];
}

// ======== 256x256 tile, BK=64, 8-wave, 4-phase pipelined bf16 GEMM (T2+T3+T4+T5) ========
// C[M][N] = A[M][K] * Bt[N][K]^T + bias. EPI: 0=bf16, 1=gelu->bf16, 2=f32(+=ACC)
// LDS 128KB: 2 slots x (A 32KB + B 32KB). Rows are 128B (64 bf16); 16B-slot swizzle
// slot' = slot ^ (row&7), applied as inverse-swizzled GLOBAL source (global_load_lds
// writes linearly) + identically swizzled ds_read (rule 21: both-sides involution).
// Read-side kk slice: slot = (kk*4+lq)^(row&7) = (lq^(row&7)) XOR kk*4  -> byte XOR kk*64.
template <int EPI, bool ACC>
__global__ __launch_bounds__(512, 2) void k_gemm256(
    const bf16* __restrict__ A, const bf16* __restrict__ Bt,
    const float* __restrict__ bias, void* __restrict__ Cout,
    int K, int lda, int ldb, int ldc) {
  __shared__ __attribute__((aligned(16))) char lds[131072];
  const int t = threadIdx.x, w = t >> 6, l = t & 63;
  const int gx = gridDim.x, nwg = gx * gridDim.y;
  int bid = blockIdx.y * gx + blockIdx.x;
  bid = (bid & 7) * (nwg >> 3) + (bid >> 3);  // XCD swizzle (nwg % 8 == 0)
  const int bm = bid / gx, bn = bid % gx;
  const int wm = w >> 2, wn = w & 3;  // 2M x 4N waves, per-wave C = 128x64
  const int lq = l >> 4, lr = l & 15;

  // ---- staging geometry (source pre-swizzled; LDS dest linear) ----
  const int srow = (w << 3) + (l >> 3);                 // tile row for j=0 (j: +64)
  const int scol = ((l & 7) ^ ((l >> 3) & 7)) << 4;     // swizzled byte-in-row
  const size_t ldab = (size_t)lda * 2, ldbb = (size_t)ldb * 2;
  const size_t ldab64 = ldab * 64, ldbb64 = ldbb * 64;
  const char* pA = (const char*)(A + (size_t)(bm * 256) * lda) + (size_t)srow * ldab + scol;
  const char* pB = (const char*)(Bt + (size_t)(bn * 256) * ldb) + (size_t)srow * ldbb + scol;
  const int ldst = w * 1024;  // wave-uniform LDS dest base (HW adds lane*16)

  // ---- fragment read addresses (swizzled) ----
  const int swz0 = (lq ^ (lr & 7)) << 4;               // kk=0 slice byte; kk=1: ^64
  const int arow = wm * 16384 + lr * 128;              // A row byte base (bits >=7)
  const int brow = 32768 + (wn >> 1) * 16384 + ((wn & 1) * 64 + lr) * 128;

  f32x4 acc[8][4];
#pragma unroll
  for (int m = 0; m < 8; ++m)
#pragma unroll
    for (int n = 0; n < 4; ++n) acc[m][n] = (f32x4){0.f, 0.f, 0.f, 0.f};

#define STAGE_A(j, slotbase)                                            \
  gload_lds16(pA + (size_t)(j)*ldab64, (slotbase) + (j)*8192 + ldst)
#define STAGE_B(j, slotbase)                                            \
  gload_lds16(pB + (size_t)(j)*ldbb64, (slotbase) + 32768 + (j)*8192 + ldst)

  // ---- prologue: stage K-tile 0 into slot 0 ----
  {
    char* s0 = lds;
    STAGE_A(0, s0); STAGE_A(1, s0); STAGE_A(2, s0); STAGE_A(3, s0);
    STAGE_B(0, s0); STAGE_B(1, s0); STAGE_B(2, s0); STAGE_B(3, s0);
    pA += 128; pB += 128;
    asm volatile("s_waitcnt vmcnt(0)" ::: "memory");
    __builtin_amdgcn_s_barrier();
    asm volatile("" ::: "memory");
  }

  const int NT = K >> 6;
  bf16x8 aF[4][2], bF01[2][2], bF23[2][2];

  for (int kt = 0; kt < NT; ++kt) {
    char* cur = lds + (kt & 1) * 65536;
    char* nxt = lds + ((kt & 1) ^ 1) * 65536;
    const char* Ac = cur + arow;
    const char* Bc = cur + brow;
    const bool pre = (kt + 1 < NT);

    // ---------- phase 0: read a(fr0-3), b(fc0-1); stage next A; MFMA q(fr0-3 x fc0-1)
#pragma unroll
    for (int fr = 0; fr < 4; ++fr)
#pragma unroll
      for (int kk = 0; kk < 2; ++kk)
        aF[fr][kk] = *(const bf16x8*)(Ac + fr * 2048 + (swz0 ^ (kk << 6)));
#pragma unroll
    for (int fc = 0; fc < 2; ++fc)
#pragma unroll
      for (int kk = 0; kk < 2; ++kk)
        bF01[fc][kk] = *(const bf16x8*)(Bc + fc * 2048 + (swz0 ^ (kk << 6)));
    if (pre) { STAGE_A(0, nxt); STAGE_A(1, nxt); STAGE_A(2, nxt); STAGE_A(3, nxt); }
    __builtin_amdgcn_s_barrier();
    __builtin_amdgcn_s_setprio(1);
#pragma unroll
    for (int fr = 0; fr < 4; ++fr)
#pragma unroll
      for (int fc = 0; fc < 2; ++fc)
#pragma unroll
        for (int kk = 0; kk < 2; ++kk)
          acc[fr][fc] = __builtin_amdgcn_mfma_f32_16x16x32_bf16(aF[fr][kk], bF01[fc][kk], acc[fr][fc], 0, 0, 0);
    __builtin_amdgcn_s_setprio(0);
    __builtin_amdgcn_s_barrier();

    // ---------- phase 1: read b(fc2-3); stage next B j0-1; MFMA q(fr0-3 x fc2-3)
#pragma unroll
    for (int fc = 0; fc < 2; ++fc)
#pragma unroll
      for (int kk = 0; kk < 2; ++kk)
        bF23[fc][kk] = *(const bf16x8*)(Bc + (2 + fc) * 2048 + (swz0 ^ (kk << 6)));
    if (pre) { STAGE_B(0, nxt); STAGE_B(1, nxt); }
    __builtin_amdgcn_s_barrier();
    __builtin_amdgcn_s_setprio(1);
#pragma unroll
    for (int fr = 0; fr < 4; ++fr)
#pragma unroll
      for (int fc = 0; fc < 2; ++fc)
#pragma unroll
        for (int kk = 0; kk < 2; ++kk)
          acc[fr][2 + fc] = __builtin_amdgcn_mfma_f32_16x16x32_bf16(aF[fr][kk], bF23[fc][kk], acc[fr][2 + fc], 0, 0, 0);
    __builtin_amdgcn_s_setprio(0);
    __builtin_amdgcn_s_barrier();

    // ---------- phase 2: read a(fr4-7); stage next B j2-3; MFMA q(fr4-7 x fc0-1)
#pragma unroll
    for (int fr = 0; fr < 4; ++fr)
#pragma unroll
      for (int kk = 0; kk < 2; ++kk)
        aF[fr][kk] = *(const bf16x8*)(Ac + (4 + fr) * 2048 + (swz0 ^ (kk << 6)));
    if (pre) { STAGE_B(2, nxt); STAGE_B(3, nxt); }
    __builtin_amdgcn_s_barrier();
    __builtin_amdgcn_s_setprio(1);
#pragma unroll
    for (int fr = 0; fr < 4; ++fr)
#pragma unroll
      for (int fc = 0; fc < 2; ++fc)
#pragma unroll
        for (int kk = 0; kk < 2; ++kk)
          acc[4 + fr][fc] = __builtin_amdgcn_mfma_f32_16x16x32_bf16(aF[fr][kk], bF01[fc][kk], acc[4 + fr][fc], 0, 0, 0);
    __builtin_amdgcn_s_setprio(0);
    __builtin_amdgcn_s_barrier();

    // ---------- phase 3: MFMA q(fr4-7 x fc2-3); drain staging; boundary barrier
    __builtin_amdgcn_s_setprio(1);
#pragma unroll
    for (int fr = 0; fr < 4; ++fr)
#pragma unroll
      for (int fc = 0; fc < 2; ++fc)
#pragma unroll
        for (int kk = 0; kk < 2; ++kk)
          acc[4 + fr][2 + fc] = __builtin_amdgcn_mfma_f32_16x16x32_bf16(aF[fr][kk], bF23[fc][kk], acc[4 + fr][2 + fc], 0, 0, 0);
    __builtin_amdgcn_s_setprio(0);
    asm volatile("s_waitcnt vmcnt(0)" ::: "memory");
    __builtin_amdgcn_s_barrier();
    asm volatile("" ::: "memory");

    if (pre) { pA += 128; pB += 128; }
  }
#undef STAGE_A
#undef STAGE_B

  // ---- epilogue ----
  const int rowb = bm * 256 + wm * 128;
  const int colb = bn * 256 + wn * 64;
#pragma unroll
  for (int fr = 0; fr < 8; ++fr) {
#pragma unroll
    for (int fc = 0; fc < 4; ++fc) {
      const int col = colb + fc * 16 + lr;
      const float bv = bias ? bias[col] : 0.0f;
#pragma unroll
      for (int i = 0; i < 4; ++i) {
        const int row = rowb + fr * 16 + lq * 4 + i;
        float v = acc[fr][fc][i] + bv;
        if (EPI == 1) v = gelu_erf(v);
        if (EPI <= 1) {
          ((bf16*)Cout)[(size_t)row * ldc + col] = __float2bfloat16(v);
        } else {
          float* Cf = (float*)Cout;
          const size_t idx = (size_t)row * ldc + col;
          if (ACC) v += Cf[idx];
          Cf[idx] = v;
        }
      }
    }
  }
}

// ---------------- attention v2: register-resident softmax (unchanged) ----------------
__global__ __launch_bounds__(256) void k_attn(const bf16* __restrict__ Qg,
                                              const bf16* __restrict__ Kg,
                                              const bf16* __restrict__ Vt,
                                              bf16* __restrict__ Og) {
  __shared__ bf16 Pl[32][520];
  __shared__ float redm[2][32];
  __shared__ float reds[2][32];
  int bid = blockIdx.y * 16 + blockIdx.x;
  bid = (bid & 7) * (4096 >> 3) + (bid >> 3);
  const int bh = bid / 16, q0 = (bid % 16) * 32;
  const int b = bh >> 3, h = bh & 7;
  const int t = threadIdx.x, w = t >> 6, l = t & 63;
  const int lq = l >> 4, lr = l & 15;
  const int rt = w & 1, ch = w >> 1;
  const int myrow = rt * 16 + lq * 4;

  const bf16* qbase = Qg + ((size_t)b * 512 + q0 + rt * 16 + lr) * 1024 + h * 128;
  bf16x8 afr[4];
#pragma unroll
  for (int d0 = 0; d0 < 4; ++d0)
    afr[d0] = *(const bf16x8*)(qbase + d0 * 32 + lq * 8);

  const bf16* kbase = Kg + (size_t)b * 512 * 1024 + h * 128;
  f32x4 sc[16];
#pragma unroll
  for (int ct = 0; ct < 16; ++ct) {
    const int col0 = ch * 256 + ct * 16;
    f32x4 acc = (f32x4){0.f, 0.f, 0.f, 0.f};
#pragma unroll
    for (int d0 = 0; d0 < 4; ++d0) {
      bf16x8 bfrg = *(const bf16x8*)(kbase + (size_t)(col0 + lr) * 1024 + d0 * 32 + lq * 8);
      acc = __builtin_amdgcn_mfma_f32_16x16x32_bf16(afr[d0], bfrg, acc, 0, 0, 0);
    }
    sc[ct] = acc;
  }

  float m4[4];
#pragma unroll
  for (int i = 0; i < 4; ++i) {
    float m = sc[0][i];
#pragma unroll
    for (int ct = 1; ct < 16; ++ct) m = fmaxf(m, sc[ct][i]);
    m4[i] = m;
  }
#pragma unroll
  for (int i = 0; i < 4; ++i) {
    m4[i] = fmaxf(m4[i], __shfl_xor(m4[i], 1));
    m4[i] = fmaxf(m4[i], __shfl_xor(m4[i], 2));
    m4[i] = fmaxf(m4[i], __shfl_xor(m4[i], 4));
    m4[i] = fmaxf(m4[i], __shfl_xor(m4[i], 8));
  }
  if (lr == 0) {
#pragma unroll
    for (int i = 0; i < 4; ++i) redm[ch][myrow + i] = m4[i];
  }
  __syncthreads();
  float fm[4];
#pragma unroll
  for (int i = 0; i < 4; ++i)
    fm[i] = fmaxf(redm[0][myrow + i], redm[1][myrow + i]);

  float s4[4] = {0.f, 0.f, 0.f, 0.f};
#pragma unroll
  for (int ct = 0; ct < 16; ++ct) {
    const int col = ch * 256 + ct * 16 + lr;
#pragma unroll
    for (int i = 0; i < 4; ++i) {
      const float e = __expf(sc[ct][i] - fm[i]);
      s4[i] += e;
      Pl[myrow + i][col] = __float2bfloat16(e);
    }
  }
#pragma unroll
  for (int i = 0; i < 4; ++i) {
    s4[i] += __shfl_xor(s4[i], 1);
    s4[i] += __shfl_xor(s4[i], 2);
    s4[i] += __shfl_xor(s4[i], 4);
    s4[i] += __shfl_xor(s4[i], 8);
  }
  if (lr == 0) {
#pragma unroll
    for (int i = 0; i < 4; ++i) reds[ch][myrow + i] = s4[i];
  }
  __syncthreads();

  const bf16* vbase = Vt + (size_t)bh * 128 * 512;
  f32x4 oacc[4];
#pragma unroll
  for (int n = 0; n < 4; ++n) oacc[n] = (f32x4){0.f, 0.f, 0.f, 0.f};
  for (int s0 = 0; s0 < 512; s0 += 32) {
    bf16x8 pa = *(const bf16x8*)&Pl[rt * 16 + lr][s0 + lq * 8];
#pragma unroll
    for (int n = 0; n < 4; ++n) {
      const int dcol = (ch * 4 + n) * 16;
      bf16x8 vb = *(const bf16x8*)(vbase + (size_t)(dcol + lr) * 512 + s0 + lq * 8);
      oacc[n] = __builtin_amdgcn_mfma_f32_16x16x32_bf16(pa, vb, oacc[n], 0, 0, 0);
    }
  }
#pragma unroll
  for (int n = 0; n < 4; ++n) {
    const int dcol = (ch * 4 + n) * 16;
#pragma unroll
    for (int i = 0; i < 4; ++i) {
      const int row = myrow + i;
      const float rs = reds[0][row] + reds[1][row];
      const float val = oacc[n][i] / rs;
      Og[((size_t)b * 512 + q0 + row) * 1024 + h * 128 + dcol + lr] = __float2bfloat16(val);
    }
  }
}

extern "C" void kernel_launch(void* const* d_in, const int* in_sizes, int n_in,
                              void* d_out, int out_size, void* d_ws, size_t ws_size,
                              hipStream_t stream) {
  (void)in_sizes; (void)n_in; (void)out_size; (void)ws_size;
  const float* x  = (const float*)d_in[0];
  const float* Wq = (const float*)d_in[1];
  const float* bq = (const float*)d_in[2];
  const float* Wk = (const float*)d_in[3];
  const float* bk = (const float*)d_in[4];
  const float* Wv = (const float*)d_in[5];
  const float* bv = (const float*)d_in[6];
  const float* W1 = (const float*)d_in[7];
  const float* b1 = (const float*)d_in[8];
  const float* W2 = (const float*)d_in[9];
  const float* b2 = (const float*)d_in[10];
  float* out = (float*)d_out;
  char* ws = (char*)d_ws;
  constexpr size_t MB = 1ull << 20;

  bf16* XB  = (bf16*)(ws + 0);
  bf16* WQT = (bf16*)(ws + 32 * MB);
  bf16* WKT = (bf16*)(ws + 34 * MB);
  bf16* WVT = (bf16*)(ws + 36 * MB);
  bf16* W1T = (bf16*)(ws + 38 * MB);
  bf16* W2T = (bf16*)(ws + 54 * MB);
  bf16* OB  = (bf16*)(ws + 70 * MB);
  bf16* QB  = (bf16*)(ws + 102 * MB);
  bf16* KB  = (bf16*)(ws + 134 * MB);
  bf16* VB  = (bf16*)(ws + 166 * MB);
  bf16* VT  = (bf16*)(ws + 0);        // overlays dead XB after QKV
  bf16* HC  = (bf16*)(ws + 102 * MB); // overlays dead QB/KB after attn

  k_cvt_bf16<<<2048, 256, 0, stream>>>(x, XB, (16384 * 1024) / 4);
  k_transpose_w<<<dim3(32, 32), 256, 0, stream>>>(Wq, WQT, 1024, 1024);
  k_transpose_w<<<dim3(32, 32), 256, 0, stream>>>(Wk, WKT, 1024, 1024);
  k_transpose_w<<<dim3(32, 32), 256, 0, stream>>>(Wv, WVT, 1024, 1024);
  k_transpose_w<<<dim3(256, 32), 256, 0, stream>>>(W1, W1T, 1024, 8192);
  k_transpose_w<<<dim3(32, 256), 256, 0, stream>>>(W2, W2T, 8192, 1024);

  // QKV projections (M=16384, N=1024, K=1024): grid (4, 64) = 256 wgs
  k_gemm256<0, false><<<dim3(4, 64), 512, 0, stream>>>(XB, WQT, bq, QB, 1024, 1024, 1024, 1024);
  k_gemm256<0, false><<<dim3(4, 64), 512, 0, stream>>>(XB, WKT, bk, KB, 1024, 1024, 1024, 1024);
  k_gemm256<0, false><<<dim3(4, 64), 512, 0, stream>>>(XB, WVT, bv, VB, 1024, 1024, 1024, 1024);

  k_transpose_v<<<dim3(16, 4, 256), 256, 0, stream>>>(VB, VT);
  k_attn<<<dim3(16, 256), 256, 0, stream>>>(QB, KB, VT, OB);

  // FFN chunked over F (4 x 2048)
  for (int chk = 0; chk < 4; ++chk) {
    k_gemm256<1, false><<<dim3(8, 64), 512, 0, stream>>>(
        OB, W1T + (size_t)chk * 2048 * 1024, b1 + chk * 2048, HC, 1024, 1024, 1024, 2048);
    if (chk == 0)
      k_gemm256<2, false><<<dim3(4, 64), 512, 0, stream>>>(
          HC, W2T + chk * 2048, b2, out, 2048, 2048, 8192, 1024);
    else
      k_gemm256<2, true><<<dim3(4, 64), 512, 0, stream>>>(
          HC, W2T + chk * 2048, nullptr, out, 2048, 2048, 8192, 1024);
  }
}

// Round 5
// 1090.808 us; speedup vs baseline: 1.4227x; 1.0103x over previous
//
#include <hip/hip_runtime.h>
#include <hip/hip_bf16.h>
#include <math.h>

typedef __attribute__((ext_vector_type(8))) short bf16x8;
typedef __attribute__((ext_vector_type(4))) float f32x4;
typedef __hip_bfloat16 bf16;

__device__ __forceinline__ void gload_lds16(const void* g, void* l) {
  __builtin_amdgcn_global_load_lds((const __attribute__((address_space(1))) void*)g,
                                   (__attribute__((address_space(3))) void*)l,
                                   16, 0, 0);
}

__device__ __forceinline__ float gelu_erf(float x) {
  return 0.5f * x * (1.0f + erff(x * 0.70710678118654752f));
}

// ---------------- convert f32 -> bf16 (vectorized) ----------------
__global__ __launch_bounds__(256) void k_cvt_bf16(const float* __restrict__ in,
                                                  bf16* __restrict__ out, int n4) {
  int i = blockIdx.x * 256 + threadIdx.x;
  const int stride = gridDim.x * 256;
  for (; i < n4; i += stride) {
    float4 v = reinterpret_cast<const float4*>(in)[i];
    bf16* o = out + (size_t)i * 4;
    o[0] = __float2bfloat16(v.x);
    o[1] = __float2bfloat16(v.y);
    o[2] = __float2bfloat16(v.z);
    o[3] = __float2bfloat16(v.w);
  }
}

// ---------------- transpose f32 [R][C] -> bf16 [C][R] ----------------
__global__ __launch_bounds__(256) void k_transpose_w(const float* __restrict__ in,
                                                     bf16* __restrict__ out,
                                                     int R, int C) {
  __shared__ float tile[32][33];
  const int c0 = blockIdx.x * 32, r0 = blockIdx.y * 32;
  const int tx = threadIdx.x & 31, ty = threadIdx.x >> 5;
  for (int i = 0; i < 32; i += 8)
    tile[ty + i][tx] = in[(size_t)(r0 + ty + i) * C + c0 + tx];
  __syncthreads();
  for (int i = 0; i < 32; i += 8)
    out[(size_t)(c0 + ty + i) * R + r0 + tx] = __float2bfloat16(tile[tx][ty + i]);
}

// ------------- per-head V transpose: [B*S][E] -> [(b*H+h)*128 + d][S] -------------
__global__ __launch_bounds__(256) void k_transpose_v(const bf16* __restrict__ Vb,
                                                     bf16* __restrict__ Vt) {
  __shared__ bf16 tile[32][34];
  const int bh = blockIdx.z;
  const int b = bh >> 3, h = bh & 7;
  const int s0 = blockIdx.x * 32, d0 = blockIdx.y * 32;
  const int tx = threadIdx.x & 31, ty = threadIdx.x >> 5;
  for (int i = 0; i < 32; i += 8)
    tile[ty + i][tx] = Vb[((size_t)b * 512 + s0 + ty + i) * 1024 + h * 128 + d0 + tx];
  __syncthreads();
  for (int i = 0; i < 32; i += 8)
    Vt[((size_t)bh * 128 + d0 + ty + i) * 512 + s0 + tx] = tile[tx][ty + i];
}

// ======== 256x256 tile, BK=64, 8-wave, 4-phase pipelined bf16 GEMM (T2+T3+T4+T5) ========
// (unchanged from round 4 — passed, absmax 0.0195)
template <int EPI, bool ACC>
__global__ __launch_bounds__(512, 2) void k_gemm256(
    const bf16* __restrict__ A, const bf16* __restrict__ Bt,
    const float* __restrict__ bias, void* __restrict__ Cout,
    int K, int lda, int ldb, int ldc) {
  __shared__ __attribute__((aligned(16))) char lds[131072];
  const int t = threadIdx.x, w = t >> 6, l = t & 63;
  const int gx = gridDim.x, nwg = gx * gridDim.y;
  int bid = blockIdx.y * gx + blockIdx.x;
  bid = (bid & 7) * (nwg >> 3) + (bid >> 3);  // XCD swizzle (nwg % 8 == 0)
  const int bm = bid / gx, bn = bid % gx;
  const int wm = w >> 2, wn = w & 3;  // 2M x 4N waves, per-wave C = 128x64
  const int lq = l >> 4, lr = l & 15;

  const int srow = (w << 3) + (l >> 3);
  const int scol = ((l & 7) ^ ((l >> 3) & 7)) << 4;
  const size_t ldab = (size_t)lda * 2, ldbb = (size_t)ldb * 2;
  const size_t ldab64 = ldab * 64, ldbb64 = ldbb * 64;
  const char* pA = (const char*)(A + (size_t)(bm * 256) * lda) + (size_t)srow * ldab + scol;
  const char* pB = (const char*)(Bt + (size_t)(bn * 256) * ldb) + (size_t)srow * ldbb + scol;
  const int ldst = w * 1024;

  const int swz0 = (lq ^ (lr & 7)) << 4;
  const int arow = wm * 16384 + lr * 128;
  const int brow = 32768 + (wn >> 1) * 16384 + ((wn & 1) * 64 + lr) * 128;

  f32x4 acc[8][4];
#pragma unroll
  for (int m = 0; m < 8; ++m)
#pragma unroll
    for (int n = 0; n < 4; ++n) acc[m][n] = (f32x4){0.f, 0.f, 0.f, 0.f};

#define STAGE_A(j, slotbase)                                            \
  gload_lds16(pA + (size_t)(j)*ldab64, (slotbase) + (j)*8192 + ldst)
#define STAGE_B(j, slotbase)                                            \
  gload_lds16(pB + (size_t)(j)*ldbb64, (slotbase) + 32768 + (j)*8192 + ldst)

  {
    char* s0 = lds;
    STAGE_A(0, s0); STAGE_A(1, s0); STAGE_A(2, s0); STAGE_A(3, s0);
    STAGE_B(0, s0); STAGE_B(1, s0); STAGE_B(2, s0); STAGE_B(3, s0);
    pA += 128; pB += 128;
    asm volatile("s_waitcnt vmcnt(0)" ::: "memory");
    __builtin_amdgcn_s_barrier();
    asm volatile("" ::: "memory");
  }

  const int NT = K >> 6;
  bf16x8 aF[4][2], bF01[2][2], bF23[2][2];

  for (int kt = 0; kt < NT; ++kt) {
    char* cur = lds + (kt & 1) * 65536;
    char* nxt = lds + ((kt & 1) ^ 1) * 65536;
    const char* Ac = cur + arow;
    const char* Bc = cur + brow;
    const bool pre = (kt + 1 < NT);

#pragma unroll
    for (int fr = 0; fr < 4; ++fr)
#pragma unroll
      for (int kk = 0; kk < 2; ++kk)
        aF[fr][kk] = *(const bf16x8*)(Ac + fr * 2048 + (swz0 ^ (kk << 6)));
#pragma unroll
    for (int fc = 0; fc < 2; ++fc)
#pragma unroll
      for (int kk = 0; kk < 2; ++kk)
        bF01[fc][kk] = *(const bf16x8*)(Bc + fc * 2048 + (swz0 ^ (kk << 6)));
    if (pre) { STAGE_A(0, nxt); STAGE_A(1, nxt); STAGE_A(2, nxt); STAGE_A(3, nxt); }
    __builtin_amdgcn_s_barrier();
    __builtin_amdgcn_s_setprio(1);
#pragma unroll
    for (int fr = 0; fr < 4; ++fr)
#pragma unroll
      for (int fc = 0; fc < 2; ++fc)
#pragma unroll
        for (int kk = 0; kk < 2; ++kk)
          acc[fr][fc] = __builtin_amdgcn_mfma_f32_16x16x32_bf16(aF[fr][kk], bF01[fc][kk], acc[fr][fc], 0, 0, 0);
    __builtin_amdgcn_s_setprio(0);
    __builtin_amdgcn_s_barrier();

#pragma unroll
    for (int fc = 0; fc < 2; ++fc)
#pragma unroll
      for (int kk = 0; kk < 2; ++kk)
        bF23[fc][kk] = *(const bf16x8*)(Bc + (2 + fc) * 2048 + (swz0 ^ (kk << 6)));
    if (pre) { STAGE_B(0, nxt); STAGE_B(1, nxt); }
    __builtin_amdgcn_s_barrier();
    __builtin_amdgcn_s_setprio(1);
#pragma unroll
    for (int fr = 0; fr < 4; ++fr)
#pragma unroll
      for (int fc = 0; fc < 2; ++fc)
#pragma unroll
        for (int kk = 0; kk < 2; ++kk)
          acc[fr][2 + fc] = __builtin_amdgcn_mfma_f32_16x16x32_bf16(aF[fr][kk], bF23[fc][kk], acc[fr][2 + fc], 0, 0, 0);
    __builtin_amdgcn_s_setprio(0);
    __builtin_amdgcn_s_barrier();

#pragma unroll
    for (int fr = 0; fr < 4; ++fr)
#pragma unroll
      for (int kk = 0; kk < 2; ++kk)
        aF[fr][kk] = *(const bf16x8*)(Ac + (4 + fr) * 2048 + (swz0 ^ (kk << 6)));
    if (pre) { STAGE_B(2, nxt); STAGE_B(3, nxt); }
    __builtin_amdgcn_s_barrier();
    __builtin_amdgcn_s_setprio(1);
#pragma unroll
    for (int fr = 0; fr < 4; ++fr)
#pragma unroll
      for (int fc = 0; fc < 2; ++fc)
#pragma unroll
        for (int kk = 0; kk < 2; ++kk)
          acc[4 + fr][fc] = __builtin_amdgcn_mfma_f32_16x16x32_bf16(aF[fr][kk], bF01[fc][kk], acc[4 + fr][fc], 0, 0, 0);
    __builtin_amdgcn_s_setprio(0);
    __builtin_amdgcn_s_barrier();

    __builtin_amdgcn_s_setprio(1);
#pragma unroll
    for (int fr = 0; fr < 4; ++fr)
#pragma unroll
      for (int fc = 0; fc < 2; ++fc)
#pragma unroll
        for (int kk = 0; kk < 2; ++kk)
          acc[4 + fr][2 + fc] = __builtin_amdgcn_mfma_f32_16x16x32_bf16(aF[fr][kk], bF23[fc][kk], acc[4 + fr][2 + fc], 0, 0, 0);
    __builtin_amdgcn_s_setprio(0);
    asm volatile("s_waitcnt vmcnt(0)" ::: "memory");
    __builtin_amdgcn_s_barrier();
    asm volatile("" ::: "memory");

    if (pre) { pA += 128; pB += 128; }
  }
#undef STAGE_A
#undef STAGE_B

  const int rowb = bm * 256 + wm * 128;
  const int colb = bn * 256 + wn * 64;
#pragma unroll
  for (int fr = 0; fr < 8; ++fr) {
#pragma unroll
    for (int fc = 0; fc < 4; ++fc) {
      const int col = colb + fc * 16 + lr;
      const float bv = bias ? bias[col] : 0.0f;
#pragma unroll
      for (int i = 0; i < 4; ++i) {
        const int row = rowb + fr * 16 + lq * 4 + i;
        float v = acc[fr][fc][i] + bv;
        if (EPI == 1) v = gelu_erf(v);
        if (EPI <= 1) {
          ((bf16*)Cout)[(size_t)row * ldc + col] = __float2bfloat16(v);
        } else {
          float* Cf = (float*)Cout;
          const size_t idx = (size_t)row * ldc + col;
          if (ACC) v += Cf[idx];
          Cf[idx] = v;
        }
      }
    }
  }
}

// ---------------- attention v3: register-pipelined fragment loads ----------------
// Same structure as v2 (4 waves, 32 q-rows, register softmax, Pl bounce); the QK^T
// and PV loops use a 4-buffer register rotation so 12-16 fragment loads stay in
// flight (counted-vmcnt idiom at register level). Addresses identical to v2.
__global__ __launch_bounds__(256) void k_attn(const bf16* __restrict__ Qg,
                                              const bf16* __restrict__ Kg,
                                              const bf16* __restrict__ Vt,
                                              bf16* __restrict__ Og) {
  __shared__ bf16 Pl[32][520];
  __shared__ float redm[2][32];
  __shared__ float reds[2][32];
  int bid = blockIdx.y * 16 + blockIdx.x;
  bid = (bid & 7) * (4096 >> 3) + (bid >> 3);
  const int bh = bid / 16, q0 = (bid % 16) * 32;
  const int b = bh >> 3, h = bh & 7;
  const int t = threadIdx.x, w = t >> 6, l = t & 63;
  const int lq = l >> 4, lr = l & 15;
  const int rt = w & 1, ch = w >> 1;
  const int myrow = rt * 16 + lq * 4;

  // Q fragments (rows rt*16+lr, k = d0*32 + lq*8)
  const bf16* qbase = Qg + ((size_t)b * 512 + q0 + rt * 16 + lr) * 1024 + h * 128;
  bf16x8 afr[4];
#pragma unroll
  for (int d0 = 0; d0 < 4; ++d0)
    afr[d0] = *(const bf16x8*)(qbase + d0 * 32 + lq * 8);

  // ---- QK^T, software-pipelined: buffers K0..K3, issue depth 16 loads ----
  const bf16* kb2 = Kg + (size_t)b * 512 * 1024 + h * 128 +
                    (size_t)(ch * 256 + lr) * 1024 + lq * 8;
  f32x4 sc[16];
  bf16x8 K0[4], K1[4], K2[4], K3[4];

#define LOADK(BUF, CT)                                                   \
  {                                                                      \
    _Pragma("unroll") for (int d0 = 0; d0 < 4; ++d0)                     \
        BUF[d0] = *(const bf16x8*)(kb2 + (CT)*16384 + d0 * 32);          \
  }
#define QKT(CT, BUF)                                                     \
  {                                                                      \
    f32x4 a = (f32x4){0.f, 0.f, 0.f, 0.f};                               \
    _Pragma("unroll") for (int d0 = 0; d0 < 4; ++d0)                     \
        a = __builtin_amdgcn_mfma_f32_16x16x32_bf16(afr[d0], BUF[d0], a, 0, 0, 0); \
    sc[CT] = a;                                                          \
  }

  LOADK(K0, 0) LOADK(K1, 1) LOADK(K2, 2) LOADK(K3, 3)
  QKT(0, K0)  LOADK(K0, 4)
  QKT(1, K1)  LOADK(K1, 5)
  QKT(2, K2)  LOADK(K2, 6)
  QKT(3, K3)  LOADK(K3, 7)
  QKT(4, K0)  LOADK(K0, 8)
  QKT(5, K1)  LOADK(K1, 9)
  QKT(6, K2)  LOADK(K2, 10)
  QKT(7, K3)  LOADK(K3, 11)
  QKT(8, K0)  LOADK(K0, 12)
  QKT(9, K1)  LOADK(K1, 13)
  QKT(10, K2) LOADK(K2, 14)
  QKT(11, K3) LOADK(K3, 15)
  QKT(12, K0) QKT(13, K1) QKT(14, K2) QKT(15, K3)
#undef LOADK
#undef QKT

  // ---- softmax (register partials + cross-lane + LDS combine), as v2 ----
  float m4[4];
#pragma unroll
  for (int i = 0; i < 4; ++i) {
    float m = sc[0][i];
#pragma unroll
    for (int ct = 1; ct < 16; ++ct) m = fmaxf(m, sc[ct][i]);
    m4[i] = m;
  }
#pragma unroll
  for (int i = 0; i < 4; ++i) {
    m4[i] = fmaxf(m4[i], __shfl_xor(m4[i], 1));
    m4[i] = fmaxf(m4[i], __shfl_xor(m4[i], 2));
    m4[i] = fmaxf(m4[i], __shfl_xor(m4[i], 4));
    m4[i] = fmaxf(m4[i], __shfl_xor(m4[i], 8));
  }
  if (lr == 0) {
#pragma unroll
    for (int i = 0; i < 4; ++i) redm[ch][myrow + i] = m4[i];
  }
  __syncthreads();
  float fm[4];
#pragma unroll
  for (int i = 0; i < 4; ++i)
    fm[i] = fmaxf(redm[0][myrow + i], redm[1][myrow + i]);

  float s4[4] = {0.f, 0.f, 0.f, 0.f};
#pragma unroll
  for (int ct = 0; ct < 16; ++ct) {
    const int col = ch * 256 + ct * 16 + lr;
#pragma unroll
    for (int i = 0; i < 4; ++i) {
      const float e = __expf(sc[ct][i] - fm[i]);
      s4[i] += e;
      Pl[myrow + i][col] = __float2bfloat16(e);
    }
  }
#pragma unroll
  for (int i = 0; i < 4; ++i) {
    s4[i] += __shfl_xor(s4[i], 1);
    s4[i] += __shfl_xor(s4[i], 2);
    s4[i] += __shfl_xor(s4[i], 4);
    s4[i] += __shfl_xor(s4[i], 8);
  }
  if (lr == 0) {
#pragma unroll
    for (int i = 0; i < 4; ++i) reds[ch][myrow + i] = s4[i];
  }
  __syncthreads();

  // ---- PV, software-pipelined: buffers V0..V3 ----
  const bf16* vb2 = Vt + (size_t)bh * 128 * 512 +
                    (size_t)(ch * 64 + lr) * 512 + lq * 8;
  f32x4 oacc[4];
#pragma unroll
  for (int n = 0; n < 4; ++n) oacc[n] = (f32x4){0.f, 0.f, 0.f, 0.f};
  bf16x8 V0[4], V1[4], V2[4], V3[4];

#define LOADV(BUF, IT)                                                   \
  {                                                                      \
    _Pragma("unroll") for (int n = 0; n < 4; ++n)                        \
        BUF[n] = *(const bf16x8*)(vb2 + (size_t)n * 16 * 512 + (IT)*32); \
  }
#define PVM(IT, BUF)                                                     \
  {                                                                      \
    bf16x8 pa = *(const bf16x8*)&Pl[rt * 16 + lr][(IT)*32 + lq * 8];     \
    _Pragma("unroll") for (int n = 0; n < 4; ++n)                        \
        oacc[n] = __builtin_amdgcn_mfma_f32_16x16x32_bf16(pa, BUF[n], oacc[n], 0, 0, 0); \
  }

  LOADV(V0, 0) LOADV(V1, 1) LOADV(V2, 2) LOADV(V3, 3)
  PVM(0, V0)  LOADV(V0, 4)
  PVM(1, V1)  LOADV(V1, 5)
  PVM(2, V2)  LOADV(V2, 6)
  PVM(3, V3)  LOADV(V3, 7)
  PVM(4, V0)  LOADV(V0, 8)
  PVM(5, V1)  LOADV(V1, 9)
  PVM(6, V2)  LOADV(V2, 10)
  PVM(7, V3)  LOADV(V3, 11)
  PVM(8, V0)  LOADV(V0, 12)
  PVM(9, V1)  LOADV(V1, 13)
  PVM(10, V2) LOADV(V2, 14)
  PVM(11, V3) LOADV(V3, 15)
  PVM(12, V0) PVM(13, V1) PVM(14, V2) PVM(15, V3)
#undef LOADV
#undef PVM

#pragma unroll
  for (int n = 0; n < 4; ++n) {
    const int dcol = (ch * 4 + n) * 16;
#pragma unroll
    for (int i = 0; i < 4; ++i) {
      const int row = myrow + i;
      const float rs = reds[0][row] + reds[1][row];
      const float val = oacc[n][i] / rs;
      Og[((size_t)b * 512 + q0 + row) * 1024 + h * 128 + dcol + lr] = __float2bfloat16(val);
    }
  }
}

extern "C" void kernel_launch(void* const* d_in, const int* in_sizes, int n_in,
                              void* d_out, int out_size, void* d_ws, size_t ws_size,
                              hipStream_t stream) {
  (void)in_sizes; (void)n_in; (void)out_size; (void)ws_size;
  const float* x  = (const float*)d_in[0];
  const float* Wq = (const float*)d_in[1];
  const float* bq = (const float*)d_in[2];
  const float* Wk = (const float*)d_in[3];
  const float* bk = (const float*)d_in[4];
  const float* Wv = (const float*)d_in[5];
  const float* bv = (const float*)d_in[6];
  const float* W1 = (const float*)d_in[7];
  const float* b1 = (const float*)d_in[8];
  const float* W2 = (const float*)d_in[9];
  const float* b2 = (const float*)d_in[10];
  float* out = (float*)d_out;
  char* ws = (char*)d_ws;
  constexpr size_t MB = 1ull << 20;

  bf16* XB  = (bf16*)(ws + 0);
  bf16* WQT = (bf16*)(ws + 32 * MB);
  bf16* WKT = (bf16*)(ws + 34 * MB);
  bf16* WVT = (bf16*)(ws + 36 * MB);
  bf16* W1T = (bf16*)(ws + 38 * MB);
  bf16* W2T = (bf16*)(ws + 54 * MB);
  bf16* OB  = (bf16*)(ws + 70 * MB);
  bf16* QB  = (bf16*)(ws + 102 * MB);
  bf16* KB  = (bf16*)(ws + 134 * MB);
  bf16* VB  = (bf16*)(ws + 166 * MB);
  bf16* VT  = (bf16*)(ws + 0);        // overlays dead XB after QKV
  bf16* HC  = (bf16*)(ws + 102 * MB); // overlays dead QB/KB after attn

  k_cvt_bf16<<<2048, 256, 0, stream>>>(x, XB, (16384 * 1024) / 4);
  k_transpose_w<<<dim3(32, 32), 256, 0, stream>>>(Wq, WQT, 1024, 1024);
  k_transpose_w<<<dim3(32, 32), 256, 0, stream>>>(Wk, WKT, 1024, 1024);
  k_transpose_w<<<dim3(32, 32), 256, 0, stream>>>(Wv, WVT, 1024, 1024);
  k_transpose_w<<<dim3(256, 32), 256, 0, stream>>>(W1, W1T, 1024, 8192);
  k_transpose_w<<<dim3(32, 256), 256, 0, stream>>>(W2, W2T, 8192, 1024);

  // QKV projections (M=16384, N=1024, K=1024): grid (4, 64) = 256 wgs
  k_gemm256<0, false><<<dim3(4, 64), 512, 0, stream>>>(XB, WQT, bq, QB, 1024, 1024, 1024, 1024);
  k_gemm256<0, false><<<dim3(4, 64), 512, 0, stream>>>(XB, WKT, bk, KB, 1024, 1024, 1024, 1024);
  k_gemm256<0, false><<<dim3(4, 64), 512, 0, stream>>>(XB, WVT, bv, VB, 1024, 1024, 1024, 1024);

  k_transpose_v<<<dim3(16, 4, 256), 256, 0, stream>>>(VB, VT);
  k_attn<<<dim3(16, 256), 256, 0, stream>>>(QB, KB, VT, OB);

  // FFN chunked over F (4 x 2048)
  for (int chk = 0; chk < 4; ++chk) {
    k_gemm256<1, false><<<dim3(8, 64), 512, 0, stream>>>(
        OB, W1T + (size_t)chk * 2048 * 1024, b1 + chk * 2048, HC, 1024, 1024, 1024, 2048);
    if (chk == 0)
      k_gemm256<2, false><<<dim3(4, 64), 512, 0, stream>>>(
          HC, W2T + chk * 2048, b2, out, 2048, 2048, 8192, 1024);
    else
      k_gemm256<2, true><<<dim3(4, 64), 512, 0, stream>>>(
          HC, W2T + chk * 2048, nullptr, out, 2048, 2048, 8192, 1024);
  }
}